// Round 11
// baseline (578.632 us; speedup 1.0000x reference)
//
#include <hip/hip_runtime.h>
#include <hip/hip_bf16.h>

// DeeperGCN (GENConv softmax-agg) on MI355X.
// R9 = R8 with the PIN4 macro-parameter-capture bug fixed (param renamed V_;
// previous name `w` was substituted into the .w member position).
// R8: force MLP weights register-resident (R7 profile: VGPR=88 < 128 needed,
// mlp2ln at 33.5 TB/s == L2 ceiling -> weights were re-fetched per node).
// waves_per_eu(2,2) + opaque-asm pin + 4-acc ILP + next-node prefetch.

static __device__ __forceinline__ float wave_sum(float v) {
    #pragma unroll
    for (int o = 32; o; o >>= 1) v += __shfl_xor(v, o);
    return v;
}

#define PIN4(V_) asm volatile("" : "+v"((V_).x), "+v"((V_).y), "+v"((V_).z), "+v"((V_).w))

#define EPB 4096
#define BCAP 4096

__global__ void zero_bcnt_k(int* __restrict__ p) { p[threadIdx.x] = 0; }

// Pass 1: block ranks 4096 contiguous edges per 128-node bucket via LDS
// atomics, reserves per-bucket global ranges, appends (src,dst) line-locally.
__global__ __launch_bounds__(256) void bucket_scatter_k(const int* __restrict__ src,
                                                        const int* __restrict__ dst,
                                                        int* __restrict__ bcnt,
                                                        int2* __restrict__ stage, int e) {
    __shared__ int lcnt[512];
    __shared__ int lbase[512];
    __shared__ int rkbuf[EPB];
    int tid = threadIdx.x;
    for (int i = tid; i < 512; i += 256) lcnt[i] = 0;
    __syncthreads();
    int i0 = blockIdx.x * EPB;
    int cnt = min(EPB, e - i0);
    for (int k = tid; k < cnt; k += 256) {
        int d = dst[i0 + k];
        rkbuf[k] = atomicAdd(&lcnt[d >> 7], 1);
    }
    __syncthreads();
    for (int i = tid; i < 512; i += 256)
        lbase[i] = lcnt[i] ? atomicAdd(&bcnt[i], lcnt[i]) : 0;
    __syncthreads();
    for (int k = tid; k < cnt; k += 256) {
        int s = src[i0 + k];
        int d = dst[i0 + k];
        int b = d >> 7;
        stage[(size_t)b * BCAP + lbase[b] + rkbuf[k]] = make_int2(s, d);
    }
}

// Pass 2: block b drains bucket b; LDS histogram+scan -> bucket-contiguous CSR
// plus offs[]/deg[] (no global scan chain).
__global__ __launch_bounds__(256) void bucket_to_csr_k(const int2* __restrict__ stage,
                                                       const int* __restrict__ bcnt,
                                                       int* __restrict__ csr,
                                                       int* __restrict__ offs,
                                                       int* __restrict__ deg, int n) {
    __shared__ int lcnt[128];
    __shared__ int loff[128];
    __shared__ int wl[128];
    int b = blockIdx.x;
    int tid = threadIdx.x;
    int base = b << 7;
    if (tid < 128) lcnt[tid] = 0;
    __syncthreads();
    int cnt = bcnt[b];
    const int2* sb = stage + (size_t)b * BCAP;
    for (int k = tid; k < cnt; k += 256)
        atomicAdd(&lcnt[sb[k].y & 127], 1);
    __syncthreads();
    if (tid < 128) loff[tid] = lcnt[tid];
    __syncthreads();
    #pragma unroll
    for (int o = 1; o < 128; o <<= 1) {
        int v = 0;
        if (tid < 128 && tid >= o) v = loff[tid - o];
        __syncthreads();
        if (tid < 128) loff[tid] += v;
        __syncthreads();
    }
    if (tid < 128) {
        int ex = loff[tid] - lcnt[tid];
        wl[tid] = ex;
        if (base + tid < n) {
            offs[base + tid] = b * BCAP + ex;
            deg[base + tid] = lcnt[tid];
        }
    }
    __syncthreads();
    for (int k = tid; k < cnt; k += 256) {
        int2 sd = sb[k];
        int slot = atomicAdd(&wl[sd.y & 127], 1);
        csr[(size_t)b * BCAP + slot] = sd.x;
    }
}

// GENConv softmax aggregation: one wave per node, lane = channel.
// Online softmax, 8-edge pipelined unroll.
__global__ __launch_bounds__(256) void conv_k(const float* __restrict__ h,
                                              const int* __restrict__ offs,
                                              const int* __restrict__ deg,
                                              const int* __restrict__ csr,
                                              const float* __restrict__ tptr,
                                              float* __restrict__ out, int n) {
    int wid = threadIdx.x >> 6, lane = threadIdx.x & 63;
    int node = blockIdx.x * 4 + wid;
    if (node >= n) return;
    float tt = tptr[0];
    int start = offs[node], d = deg[node];
    float m = -__builtin_huge_valf(), num = 0.f, den = 0.f;
    int i = 0;
    for (; i + 8 <= d; i += 8) {
        int sx[8];
        float v[8];
        #pragma unroll
        for (int q = 0; q < 8; q++) sx[q] = csr[start + i + q];
        #pragma unroll
        for (int q = 0; q < 8; q++) v[q] = h[(size_t)sx[q] * 64 + lane];
        float msg[8], w[8];
        float wm = m;
        #pragma unroll
        for (int q = 0; q < 8; q++) {
            msg[q] = fmaxf(v[q], 0.f) + 1e-7f;
            w[q] = msg[q] * tt;
            wm = fmaxf(wm, w[q]);
        }
        float sc = __expf(m - wm);
        num *= sc; den *= sc;
        #pragma unroll
        for (int q = 0; q < 8; q++) {
            float p = __expf(w[q] - wm);
            num += msg[q] * p;
            den += p;
        }
        m = wm;
    }
    for (; i + 4 <= d; i += 4) {
        int s0 = csr[start + i],     s1 = csr[start + i + 1];
        int s2 = csr[start + i + 2], s3 = csr[start + i + 3];
        float v0 = h[(size_t)s0 * 64 + lane];
        float v1 = h[(size_t)s1 * 64 + lane];
        float v2 = h[(size_t)s2 * 64 + lane];
        float v3 = h[(size_t)s3 * 64 + lane];
        float msg0 = fmaxf(v0, 0.f) + 1e-7f;
        float msg1 = fmaxf(v1, 0.f) + 1e-7f;
        float msg2 = fmaxf(v2, 0.f) + 1e-7f;
        float msg3 = fmaxf(v3, 0.f) + 1e-7f;
        float w0 = msg0 * tt, w1 = msg1 * tt, w2 = msg2 * tt, w3 = msg3 * tt;
        float nm = fmaxf(fmaxf(m, fmaxf(w0, w1)), fmaxf(w2, w3));
        float sc = __expf(m - nm);
        float p0 = __expf(w0 - nm), p1 = __expf(w1 - nm);
        float p2 = __expf(w2 - nm), p3 = __expf(w3 - nm);
        num = num * sc + (msg0 * p0 + msg1 * p1) + (msg2 * p2 + msg3 * p3);
        den = den * sc + (p0 + p1) + (p2 + p3);
        m = nm;
    }
    for (; i < d; i++) {
        int s0 = csr[start + i];
        float v0 = h[(size_t)s0 * 64 + lane];
        float msg0 = fmaxf(v0, 0.f) + 1e-7f;
        float w0 = msg0 * tt;
        float nm = fmaxf(m, w0);
        float sc = __expf(m - nm);
        float p0 = __expf(w0 - nm);
        num = num * sc + msg0 * p0;
        den = den * sc + p0;
        m = nm;
    }
    float agg = num / (den + 1e-16f);
    out[(size_t)node * 64 + lane] = agg + h[(size_t)node * 64 + lane];
}

// GEMM1 + LN + ReLU: r[node,0:128] = relu(LN(in[node,:] @ W1^T + b1))
// Lane owns output channels (lane, lane+64); W1 rows pinned in VGPRs.
__global__ __attribute__((amdgpu_flat_work_group_size(256, 256),
                          amdgpu_waves_per_eu(2, 2)))
void mlp1_k(const float* __restrict__ in,
            const float* __restrict__ W1,
            const float* __restrict__ b1,
            const float* __restrict__ mg,
            const float* __restrict__ mb,
            float* __restrict__ r, int n) {
    __shared__ float zs[4][64];
    int wid = threadIdx.x >> 6, lane = threadIdx.x & 63;

    const float4* W1v = (const float4*)W1;
    float4 wa[16], wb[16];
    #pragma unroll
    for (int q = 0; q < 16; q++) {
        wa[q] = W1v[lane * 16 + q];          // row `lane`   of W1 [128][64]
        wb[q] = W1v[(lane + 64) * 16 + q];   // row `lane+64`
        PIN4(wa[q]); PIN4(wb[q]);            // opaque: cannot be re-fetched
    }
    float ba = b1[lane], bb = b1[lane + 64];
    float ga = mg[lane], gb = mg[lane + 64];
    float ca = mb[lane], cb = mb[lane + 64];

    const int stride = gridDim.x * 4;
    int node = blockIdx.x * 4 + wid;
    float z = (node < n) ? in[(size_t)node * 64 + lane] : 0.f;
    while (node < n) {
        zs[wid][lane] = z;
        int nxt = node + stride;
        int pidx = nxt < n ? nxt : node;
        float z2 = in[(size_t)pidx * 64 + lane];   // prefetch next node
        const float4* z4 = (const float4*)zs[wid];
        float a0 = ba, a1 = 0.f, b0 = bb, b1v = 0.f;
        #pragma unroll
        for (int q = 0; q < 16; q += 2) {
            float4 za = z4[q], zb = z4[q + 1];     // uniform broadcast reads
            a0 += wa[q].x * za.x + wa[q].y * za.y + wa[q].z * za.z + wa[q].w * za.w;
            b0 += wb[q].x * za.x + wb[q].y * za.y + wb[q].z * za.z + wb[q].w * za.w;
            a1 += wa[q+1].x * zb.x + wa[q+1].y * zb.y + wa[q+1].z * zb.z + wa[q+1].w * zb.w;
            b1v += wb[q+1].x * zb.x + wb[q+1].y * zb.y + wb[q+1].z * zb.z + wb[q+1].w * zb.w;
        }
        float ha = a0 + a1, hb = b0 + b1v;
        float mu = wave_sum(ha + hb) * (1.f / 128.f);
        float da = ha - mu, db = hb - mu;
        float rstd = rsqrtf(wave_sum(da * da + db * db) * (1.f / 128.f) + 1e-5f);
        float ra = fmaxf(da * rstd * ga + ca, 0.f);
        float rb = fmaxf(db * rstd * gb + cb, 0.f);
        r[(size_t)node * 128 + lane] = ra;
        r[(size_t)node * 128 + 64 + lane] = rb;
        node = nxt; z = z2;
    }
}

// GEMM2 + bias (+residual) + fused next-LN+ReLU. W2 row pinned in VGPRs.
// WX: also store x_new (final layer writes only d_out).
template <int RES, int WX>
__global__ __attribute__((amdgpu_flat_work_group_size(256, 256),
                          amdgpu_waves_per_eu(2, 2)))
void mlp2ln_k(const float* __restrict__ r,
              const float* __restrict__ W2,
              const float* __restrict__ b2,
              const float* __restrict__ g,
              const float* __restrict__ bb,
              float* __restrict__ xio,
              float* __restrict__ hout, int n) {
    __shared__ float rs[4][128];
    int wid = threadIdx.x >> 6, lane = threadIdx.x & 63;

    const float4* W2v = (const float4*)W2;
    float4 w[32];
    #pragma unroll
    for (int q = 0; q < 32; q++) {
        w[q] = W2v[lane * 32 + q];           // row `lane` of W2 [64][128]
        PIN4(w[q]);
    }
    float bz = b2[lane];
    float gl = g[lane], bl = bb[lane];

    const int stride = gridDim.x * 4;
    int node = blockIdx.x * 4 + wid;
    float rA = 0.f, rB = 0.f, res = 0.f;
    if (node < n) {
        rA = r[(size_t)node * 128 + lane];
        rB = r[(size_t)node * 128 + 64 + lane];
        if (RES) res = xio[(size_t)node * 64 + lane];
    }
    while (node < n) {
        rs[wid][lane] = rA;
        rs[wid][64 + lane] = rB;
        int nxt = node + stride;
        int pidx = nxt < n ? nxt : node;
        float rA2 = r[(size_t)pidx * 128 + lane];          // prefetch next node
        float rB2 = r[(size_t)pidx * 128 + 64 + lane];
        float res2 = RES ? xio[(size_t)pidx * 64 + lane] : 0.f;
        const float4* r4 = (const float4*)rs[wid];
        float acc0 = bz, acc1 = 0.f, acc2 = 0.f, acc3 = 0.f;
        #pragma unroll
        for (int q = 0; q < 32; q += 4) {
            float4 v0 = r4[q], v1 = r4[q + 1], v2 = r4[q + 2], v3 = r4[q + 3];
            acc0 += w[q].x * v0.x + w[q].y * v0.y + w[q].z * v0.z + w[q].w * v0.w;
            acc1 += w[q+1].x * v1.x + w[q+1].y * v1.y + w[q+1].z * v1.z + w[q+1].w * v1.w;
            acc2 += w[q+2].x * v2.x + w[q+2].y * v2.y + w[q+2].z * v2.z + w[q+2].w * v2.w;
            acc3 += w[q+3].x * v3.x + w[q+3].y * v3.y + w[q+3].z * v3.z + w[q+3].w * v3.w;
        }
        float acc = (acc0 + acc1) + (acc2 + acc3);
        if (RES) acc += res;
        if (WX) xio[(size_t)node * 64 + lane] = acc;
        float mu = wave_sum(acc) * (1.f / 64.f);
        float dv = acc - mu;
        float var = wave_sum(dv * dv) * (1.f / 64.f);
        float rr = dv * rsqrtf(var + 1e-5f);
        hout[(size_t)node * 64 + lane] = fmaxf(rr * gl + bl, 0.f);
        node = nxt; rA = rA2; rB = rB2; res = res2;
    }
}

extern "C" void kernel_launch(void* const* d_in, const int* in_sizes, int n_in,
                              void* d_out, int out_size, void* d_ws, size_t ws_size,
                              hipStream_t stream) {
    const float* x   = (const float*)d_in[0];
    const int*   ei  = (const int*)d_in[1];
    const float* t   = (const float*)d_in[2];
    const float* W1  = (const float*)d_in[3];
    const float* b1  = (const float*)d_in[4];
    const float* mg  = (const float*)d_in[5];
    const float* mb  = (const float*)d_in[6];
    const float* W2  = (const float*)d_in[7];
    const float* b2  = (const float*)d_in[8];
    const float* lng = (const float*)d_in[9];
    const float* lnb = (const float*)d_in[10];

    int n = in_sizes[0] / 64;
    int e = in_sizes[1] / 2;
    const int* src = ei;
    const int* dst = ei + e;

    char* ws = (char*)d_ws;
    size_t off = 0;
    auto alloc = [&](size_t bytes) -> void* {
        void* p = ws + off;
        off = (off + bytes + 255) & ~(size_t)255;
        return p;
    };
    int*   bcnt  = (int*)alloc(512 * 4);
    int*   offs  = (int*)alloc((size_t)n * 4);
    int*   deg   = (int*)alloc((size_t)n * 4);
    int*   csr   = (int*)alloc((size_t)512 * BCAP * 4);
    float* xcur  = (float*)alloc((size_t)n * 64 * 4);
    float* hin   = (float*)alloc((size_t)n * 64 * 4);
    float* tmp   = (float*)alloc((size_t)n * 64 * 4);
    float* rbuf  = (float*)alloc((size_t)n * 128 * 4);
    int2*  stage = (int2*)rbuf;   // consumed before rbuf is first written

    int nbuck = (n + 127) >> 7;
    zero_bcnt_k<<<1, 512, 0, stream>>>(bcnt);
    bucket_scatter_k<<<(e + EPB - 1) / EPB, 256, 0, stream>>>(src, dst, bcnt, stage, e);
    bucket_to_csr_k<<<nbuck, 256, 0, stream>>>(stage, bcnt, csr, offs, deg, n);

    int nodeBlocks = (n + 3) / 4;
    const int mlpGrid = 512;   // 2 blocks/CU, matches waves_per_eu(2,2)

    // layer 0: x = mlp(conv(x)); hin = relu(LN_1(x))
    conv_k<<<nodeBlocks, 256, 0, stream>>>(x, offs, deg, csr, t + 0, tmp, n);
    mlp1_k<<<mlpGrid, 256, 0, stream>>>(tmp, W1, b1, mg, mb, rbuf, n);
    mlp2ln_k<0, 1><<<mlpGrid, 256, 0, stream>>>(rbuf, W2, b2, lng + 64, lnb + 64,
                                                xcur, hin, n);
    // layers 1..2: x += mlp(conv(hin)); hin = relu(LN_{i+1}(x))
    for (int i = 1; i <= 2; i++) {
        conv_k<<<nodeBlocks, 256, 0, stream>>>(hin, offs, deg, csr, t + i, tmp, n);
        mlp1_k<<<mlpGrid, 256, 0, stream>>>(tmp, W1 + (size_t)i * 8192, b1 + i * 128,
                                            mg + i * 128, mb + i * 128, rbuf, n);
        mlp2ln_k<1, 1><<<mlpGrid, 256, 0, stream>>>(rbuf, W2 + (size_t)i * 8192, b2 + i * 64,
                                                    lng + (i + 1) * 64, lnb + (i + 1) * 64,
                                                    xcur, hin, n);
    }
    // layer 3: x += mlp(conv(hin)); d_out = relu(LN_0(x))
    conv_k<<<nodeBlocks, 256, 0, stream>>>(hin, offs, deg, csr, t + 3, tmp, n);
    mlp1_k<<<mlpGrid, 256, 0, stream>>>(tmp, W1 + (size_t)3 * 8192, b1 + 3 * 128,
                                        mg + 3 * 128, mb + 3 * 128, rbuf, n);
    mlp2ln_k<1, 0><<<mlpGrid, 256, 0, stream>>>(rbuf, W2 + (size_t)3 * 8192, b2 + 3 * 64,
                                                lng, lnb, xcur, (float*)d_out, n);
}

// Round 12
// 332.424 us; speedup vs baseline: 1.7406x; 1.7406x over previous
//
#include <hip/hip_runtime.h>
#include <hip/hip_bf16.h>

// DeeperGCN (GENConv softmax-agg) on MI355X.
// R12: fused MFMA MLP (one kernel per layer): GEMM1(transposed)+LN+ReLU+GEMM2
// +bias+residual+next-LN in one pass. bf16 matmul inputs, f32 accum/residual.
// R9 post-mortem: scalar weight-stationary MLP is VGPR-bound (128 regs of
// weights/lane, occupancy collapse, MfmaUtil=0). Matrix cores were idle.

typedef unsigned int uint;
typedef __attribute__((ext_vector_type(8))) short bf16x8;
typedef __attribute__((ext_vector_type(4))) float f32x4;

static __device__ __forceinline__ float wave_sum(float v) {
    #pragma unroll
    for (int o = 32; o; o >>= 1) v += __shfl_xor(v, o);
    return v;
}

static __device__ __forceinline__ uint f2bf(float f) {
    uint u = __builtin_bit_cast(uint, f);
    return (u + 0x7FFFu + ((u >> 16) & 1u)) >> 16;   // RNE
}

static __device__ __forceinline__ uint4 pk4(float4 a, float4 b) {
    uint4 p;
    p.x = f2bf(a.x) | (f2bf(a.y) << 16);
    p.y = f2bf(a.z) | (f2bf(a.w) << 16);
    p.z = f2bf(b.x) | (f2bf(b.y) << 16);
    p.w = f2bf(b.z) | (f2bf(b.w) << 16);
    return p;
}

union FragU { uint4 u; bf16x8 v; };

#define EPB 4096
#define BCAP 4096

__global__ void zero_bcnt_k(int* __restrict__ p) { p[threadIdx.x] = 0; }

// CSR pass 1: per-4096-edge block, rank per 128-node bucket via LDS atomics,
// reserve global ranges, append (src,dst) line-locally into staging.
__global__ __launch_bounds__(256) void bucket_scatter_k(const int* __restrict__ src,
                                                        const int* __restrict__ dst,
                                                        int* __restrict__ bcnt,
                                                        int2* __restrict__ stage, int e) {
    __shared__ int lcnt[512];
    __shared__ int lbase[512];
    __shared__ int rkbuf[EPB];
    int tid = threadIdx.x;
    for (int i = tid; i < 512; i += 256) lcnt[i] = 0;
    __syncthreads();
    int i0 = blockIdx.x * EPB;
    int cnt = min(EPB, e - i0);
    for (int k = tid; k < cnt; k += 256) {
        int d = dst[i0 + k];
        rkbuf[k] = atomicAdd(&lcnt[d >> 7], 1);
    }
    __syncthreads();
    for (int i = tid; i < 512; i += 256)
        lbase[i] = lcnt[i] ? atomicAdd(&bcnt[i], lcnt[i]) : 0;
    __syncthreads();
    for (int k = tid; k < cnt; k += 256) {
        int s = src[i0 + k];
        int d = dst[i0 + k];
        int b = d >> 7;
        stage[(size_t)b * BCAP + lbase[b] + rkbuf[k]] = make_int2(s, d);
    }
}

// CSR pass 2: block b drains bucket b; LDS histogram+scan -> bucket-contiguous
// CSR plus offs[]/deg[].
__global__ __launch_bounds__(256) void bucket_to_csr_k(const int2* __restrict__ stage,
                                                       const int* __restrict__ bcnt,
                                                       int* __restrict__ csr,
                                                       int* __restrict__ offs,
                                                       int* __restrict__ deg, int n) {
    __shared__ int lcnt[128];
    __shared__ int loff[128];
    __shared__ int wl[128];
    int b = blockIdx.x;
    int tid = threadIdx.x;
    int base = b << 7;
    if (tid < 128) lcnt[tid] = 0;
    __syncthreads();
    int cnt = bcnt[b];
    const int2* sb = stage + (size_t)b * BCAP;
    for (int k = tid; k < cnt; k += 256)
        atomicAdd(&lcnt[sb[k].y & 127], 1);
    __syncthreads();
    if (tid < 128) loff[tid] = lcnt[tid];
    __syncthreads();
    #pragma unroll
    for (int o = 1; o < 128; o <<= 1) {
        int v = 0;
        if (tid < 128 && tid >= o) v = loff[tid - o];
        __syncthreads();
        if (tid < 128) loff[tid] += v;
        __syncthreads();
    }
    if (tid < 128) {
        int ex = loff[tid] - lcnt[tid];
        wl[tid] = ex;
        if (base + tid < n) {
            offs[base + tid] = b * BCAP + ex;
            deg[base + tid] = lcnt[tid];
        }
    }
    __syncthreads();
    for (int k = tid; k < cnt; k += 256) {
        int2 sd = sb[k];
        int slot = atomicAdd(&wl[sd.y & 127], 1);
        csr[(size_t)b * BCAP + slot] = sd.x;
    }
}

// GENConv softmax aggregation: one wave per node, lane = channel.
// Online softmax, 8-edge pipelined unroll.
__global__ __launch_bounds__(256) void conv_k(const float* __restrict__ h,
                                              const int* __restrict__ offs,
                                              const int* __restrict__ deg,
                                              const int* __restrict__ csr,
                                              const float* __restrict__ tptr,
                                              float* __restrict__ out, int n) {
    int wid = threadIdx.x >> 6, lane = threadIdx.x & 63;
    int node = blockIdx.x * 4 + wid;
    if (node >= n) return;
    float tt = tptr[0];
    int start = offs[node], d = deg[node];
    float m = -__builtin_huge_valf(), num = 0.f, den = 0.f;
    int i = 0;
    for (; i + 8 <= d; i += 8) {
        int sx[8];
        float v[8];
        #pragma unroll
        for (int q = 0; q < 8; q++) sx[q] = csr[start + i + q];
        #pragma unroll
        for (int q = 0; q < 8; q++) v[q] = h[(size_t)sx[q] * 64 + lane];
        float msg[8], w[8];
        float wm = m;
        #pragma unroll
        for (int q = 0; q < 8; q++) {
            msg[q] = fmaxf(v[q], 0.f) + 1e-7f;
            w[q] = msg[q] * tt;
            wm = fmaxf(wm, w[q]);
        }
        float sc = __expf(m - wm);
        num *= sc; den *= sc;
        #pragma unroll
        for (int q = 0; q < 8; q++) {
            float p = __expf(w[q] - wm);
            num += msg[q] * p;
            den += p;
        }
        m = wm;
    }
    for (; i + 4 <= d; i += 4) {
        int s0 = csr[start + i],     s1 = csr[start + i + 1];
        int s2 = csr[start + i + 2], s3 = csr[start + i + 3];
        float v0 = h[(size_t)s0 * 64 + lane];
        float v1 = h[(size_t)s1 * 64 + lane];
        float v2 = h[(size_t)s2 * 64 + lane];
        float v3 = h[(size_t)s3 * 64 + lane];
        float msg0 = fmaxf(v0, 0.f) + 1e-7f;
        float msg1 = fmaxf(v1, 0.f) + 1e-7f;
        float msg2 = fmaxf(v2, 0.f) + 1e-7f;
        float msg3 = fmaxf(v3, 0.f) + 1e-7f;
        float w0 = msg0 * tt, w1 = msg1 * tt, w2 = msg2 * tt, w3 = msg3 * tt;
        float nm = fmaxf(fmaxf(m, fmaxf(w0, w1)), fmaxf(w2, w3));
        float sc = __expf(m - nm);
        float p0 = __expf(w0 - nm), p1 = __expf(w1 - nm);
        float p2 = __expf(w2 - nm), p3 = __expf(w3 - nm);
        num = num * sc + (msg0 * p0 + msg1 * p1) + (msg2 * p2 + msg3 * p3);
        den = den * sc + (p0 + p1) + (p2 + p3);
        m = nm;
    }
    for (; i < d; i++) {
        int s0 = csr[start + i];
        float v0 = h[(size_t)s0 * 64 + lane];
        float msg0 = fmaxf(v0, 0.f) + 1e-7f;
        float w0 = msg0 * tt;
        float nm = fmaxf(m, w0);
        float sc = __expf(m - nm);
        float p0 = __expf(w0 - nm);
        num = num * sc + msg0 * p0;
        den = den * sc + p0;
        m = nm;
    }
    float agg = num / (den + 1e-16f);
    out[(size_t)node * 64 + lane] = agg + h[(size_t)node * 64 + lane];
}

// Fused MLP: per 16-node tile (one wave), all on matrix cores, transposed:
//   C1T[j][node]   = W1 . Z^T   (8 j-tiles x K=64  -> 16 MFMA)
//   r = relu(LN(C1T + b1))  -- LN per node = in-lane sum + shfl_xor(16,32)
//   C2T[co][node]  = W2 . R^T   (4 co-tiles x K=128 -> 16 MFMA)
//   out = C2T + b2 (+xio residual); optionally store xio; hout = relu(LN(out))
// Weights staged once per block into LDS as packed bf16 fragments.
// R^T bounce through per-wave XOR-swizzled LDS ([node][k], byte^=(node&15)<<4).
template <int RES, int WX>
__global__ __launch_bounds__(256) void mlp_fused_k(
        const float* __restrict__ zin,
        const float* __restrict__ W1, const float* __restrict__ b1,
        const float* __restrict__ mg, const float* __restrict__ mb,
        const float* __restrict__ W2, const float* __restrict__ b2,
        const float* __restrict__ g2, const float* __restrict__ bb2,
        float* __restrict__ xio, float* __restrict__ hout, int n) {
    __shared__ uint lw1[16 * 64 * 4];   // 16 frags (jt,ks) x 64 lanes x 16B
    __shared__ uint lw2[16 * 64 * 4];   // 16 frags (ct,ks)
    __shared__ uint lrt[4 * 1024];      // per-wave 4KB R^T bounce
    __shared__ float sp[576];           // b1[128] mg[128] mb[128] b2[64] g[64] bb[64]
    int tid = threadIdx.x;
    int wid = tid >> 6, lane = tid & 63;
    int nodeL = lane & 15, g = lane >> 4;

    #pragma unroll
    for (int q = 0; q < 4; q++) {                    // W1 frags: f = jt*2+ks
        int f = wid * 4 + q;
        int jt = f >> 1, ks = f & 1;
        const float* s = W1 + (jt * 16 + nodeL) * 64 + ks * 32 + g * 8;
        float4 a = *(const float4*)s, b = *(const float4*)(s + 4);
        *(uint4*)&lw1[(f * 64 + lane) * 4] = pk4(a, b);
    }
    #pragma unroll
    for (int q = 0; q < 4; q++) {                    // W2 frags: f = ct*4+ks
        int f = wid * 4 + q;
        int ct = f >> 2, ks = f & 3;
        const float* s = W2 + (ct * 16 + nodeL) * 128 + ks * 32 + g * 8;
        float4 a = *(const float4*)s, b = *(const float4*)(s + 4);
        *(uint4*)&lw2[(f * 64 + lane) * 4] = pk4(a, b);
    }
    if (tid < 128) { sp[tid] = b1[tid]; sp[128 + tid] = mg[tid]; sp[256 + tid] = mb[tid]; }
    else if (tid < 192) {
        int i = tid - 128;
        sp[384 + i] = b2[i]; sp[448 + i] = g2[i]; sp[512 + i] = bb2[i];
    }
    __syncthreads();

    uint* rt = lrt + wid * 1024;
    int nt = (n + 15) >> 4;
    for (int tile = blockIdx.x * 4 + wid; tile < nt; tile += gridDim.x * 4) {
        int node = tile * 16 + nodeL;
        int rnode = min(node, n - 1);
        const float* zp = zin + (size_t)rnode * 64 + g * 8;
        float4 z0 = *(const float4*)zp,        z1 = *(const float4*)(zp + 4);
        float4 z2 = *(const float4*)(zp + 32), z3 = *(const float4*)(zp + 36);
        FragU zb0, zb1;
        zb0.u = pk4(z0, z1);
        zb1.u = pk4(z2, z3);

        f32x4 acc[8];
        #pragma unroll
        for (int jt = 0; jt < 8; jt++) {
            FragU wA, wB;
            wA.u = *(const uint4*)&lw1[((jt * 2 + 0) * 64 + lane) * 4];
            wB.u = *(const uint4*)&lw1[((jt * 2 + 1) * 64 + lane) * 4];
            f32x4 c = {0.f, 0.f, 0.f, 0.f};
            c = __builtin_amdgcn_mfma_f32_16x16x32_bf16(wA.v, zb0.v, c, 0, 0, 0);
            c = __builtin_amdgcn_mfma_f32_16x16x32_bf16(wB.v, zb1.v, c, 0, 0, 0);
            acc[jt] = c;
        }
        // bias + LN(128) stats; lane holds j = jt*16+4g+jj for its node
        float s1 = 0.f, s2 = 0.f;
        float h[8][4];
        #pragma unroll
        for (int jt = 0; jt < 8; jt++)
            #pragma unroll
            for (int jj = 0; jj < 4; jj++) {
                float v = acc[jt][jj] + sp[jt * 16 + 4 * g + jj];
                h[jt][jj] = v; s1 += v; s2 += v * v;
            }
        s1 += __shfl_xor(s1, 16); s1 += __shfl_xor(s1, 32);
        s2 += __shfl_xor(s2, 16); s2 += __shfl_xor(s2, 32);
        float mu = s1 * (1.f / 128.f);
        float var = s2 * (1.f / 128.f) - mu * mu;
        float rstd = rsqrtf(fmaxf(var, 0.f) + 1e-5f);
        // r = relu(LN) -> bf16 pairs -> swizzled R^T bounce
        #pragma unroll
        for (int jt = 0; jt < 8; jt++)
            #pragma unroll
            for (int jp = 0; jp < 2; jp++) {
                int j0 = jt * 16 + 4 * g + 2 * jp;
                float r0 = fmaxf((h[jt][2 * jp] - mu) * rstd * sp[128 + j0] + sp[256 + j0], 0.f);
                float r1 = fmaxf((h[jt][2 * jp + 1] - mu) * rstd * sp[128 + j0 + 1] + sp[256 + j0 + 1], 0.f);
                uint val = f2bf(r0) | (f2bf(r1) << 16);
                uint byte = (uint)(nodeL * 256 + jt * 32 + g * 8 + jp * 4) ^ ((uint)nodeL << 4);
                rt[byte >> 2] = val;
            }
        // B2 fragments: col=node, k = ks*32 + g*8 + 0..7 (contiguous in [node][k])
        FragU rb[4];
        #pragma unroll
        for (int ks = 0; ks < 4; ks++) {
            uint byte = (uint)(nodeL * 256 + ks * 64 + g * 16) ^ ((uint)nodeL << 4);
            rb[ks].u = *(const uint4*)((const char*)rt + byte);
        }
        f32x4 acc2[4];
        #pragma unroll
        for (int ct = 0; ct < 4; ct++) {
            f32x4 c = {0.f, 0.f, 0.f, 0.f};
            #pragma unroll
            for (int ks = 0; ks < 4; ks++) {
                FragU wf;
                wf.u = *(const uint4*)&lw2[((ct * 4 + ks) * 64 + lane) * 4];
                c = __builtin_amdgcn_mfma_f32_16x16x32_bf16(wf.v, rb[ks].v, c, 0, 0, 0);
            }
            acc2[ct] = c;
        }
        // epilogue: bias + residual + (store x) + LN(64) + relu -> hout
        if (node < n) {   // uniform across shfl partners (same node)
            float o[4][4];
            float t1 = 0.f, t2 = 0.f;
            #pragma unroll
            for (int ct = 0; ct < 4; ct++) {
                float4 res;
                if (RES) res = *(const float4*)(xio + (size_t)node * 64 + ct * 16 + 4 * g);
                #pragma unroll
                for (int jj = 0; jj < 4; jj++) {
                    float v = acc2[ct][jj] + sp[384 + ct * 16 + 4 * g + jj];
                    if (RES) v += ((const float*)&res)[jj];
                    o[ct][jj] = v; t1 += v; t2 += v * v;
                }
                if (WX) *(float4*)(xio + (size_t)node * 64 + ct * 16 + 4 * g) =
                    make_float4(o[ct][0], o[ct][1], o[ct][2], o[ct][3]);
            }
            t1 += __shfl_xor(t1, 16); t1 += __shfl_xor(t1, 32);
            t2 += __shfl_xor(t2, 16); t2 += __shfl_xor(t2, 32);
            float mu2 = t1 * (1.f / 64.f);
            float var2 = t2 * (1.f / 64.f) - mu2 * mu2;
            float rs2 = rsqrtf(fmaxf(var2, 0.f) + 1e-5f);
            #pragma unroll
            for (int ct = 0; ct < 4; ct++) {
                float4 ov;
                #pragma unroll
                for (int jj = 0; jj < 4; jj++) {
                    int co = ct * 16 + 4 * g + jj;
                    ((float*)&ov)[jj] =
                        fmaxf((o[ct][jj] - mu2) * rs2 * sp[448 + co] + sp[512 + co], 0.f);
                }
                *(float4*)(hout + (size_t)node * 64 + ct * 16 + 4 * g) = ov;
            }
        }
    }
}

extern "C" void kernel_launch(void* const* d_in, const int* in_sizes, int n_in,
                              void* d_out, int out_size, void* d_ws, size_t ws_size,
                              hipStream_t stream) {
    const float* x   = (const float*)d_in[0];
    const int*   ei  = (const int*)d_in[1];
    const float* t   = (const float*)d_in[2];
    const float* W1  = (const float*)d_in[3];
    const float* b1  = (const float*)d_in[4];
    const float* mg  = (const float*)d_in[5];
    const float* mb  = (const float*)d_in[6];
    const float* W2  = (const float*)d_in[7];
    const float* b2  = (const float*)d_in[8];
    const float* lng = (const float*)d_in[9];
    const float* lnb = (const float*)d_in[10];

    int n = in_sizes[0] / 64;
    int e = in_sizes[1] / 2;
    const int* src = ei;
    const int* dst = ei + e;

    char* ws = (char*)d_ws;
    size_t off = 0;
    auto alloc = [&](size_t bytes) -> void* {
        void* p = ws + off;
        off = (off + bytes + 255) & ~(size_t)255;
        return p;
    };
    int*   bcnt  = (int*)alloc(512 * 4);
    int*   offs  = (int*)alloc((size_t)n * 4);
    int*   deg   = (int*)alloc((size_t)n * 4);
    int*   csr   = (int*)alloc((size_t)512 * BCAP * 4);
    float* xcur  = (float*)alloc((size_t)n * 64 * 4);
    float* hin   = (float*)alloc((size_t)n * 64 * 4);
    float* tmp   = (float*)alloc((size_t)n * 64 * 4);
    int2*  stage = (int2*)alloc((size_t)512 * BCAP * 8);

    int nbuck = (n + 127) >> 7;
    zero_bcnt_k<<<1, 512, 0, stream>>>(bcnt);
    bucket_scatter_k<<<(e + EPB - 1) / EPB, 256, 0, stream>>>(src, dst, bcnt, stage, e);
    bucket_to_csr_k<<<nbuck, 256, 0, stream>>>(stage, bcnt, csr, offs, deg, n);

    int nodeBlocks = (n + 3) / 4;
    const int mlpGrid = 512;   // persistent; 4 waves/block, wave = 16-node tile

    // layer 0: x = mlp(conv(x)); hin = relu(LN_1(x))
    conv_k<<<nodeBlocks, 256, 0, stream>>>(x, offs, deg, csr, t + 0, tmp, n);
    mlp_fused_k<0, 1><<<mlpGrid, 256, 0, stream>>>(tmp, W1, b1, mg, mb, W2, b2,
                                                   lng + 64, lnb + 64, xcur, hin, n);
    // layers 1..2: x += mlp(conv(hin)); hin = relu(LN_{i+1}(x))
    for (int i = 1; i <= 2; i++) {
        conv_k<<<nodeBlocks, 256, 0, stream>>>(hin, offs, deg, csr, t + i, tmp, n);
        mlp_fused_k<1, 1><<<mlpGrid, 256, 0, stream>>>(
            tmp, W1 + (size_t)i * 8192, b1 + i * 128, mg + i * 128, mb + i * 128,
            W2 + (size_t)i * 8192, b2 + i * 64,
            lng + (i + 1) * 64, lnb + (i + 1) * 64, xcur, hin, n);
    }
    // layer 3: x += mlp(conv(hin)); d_out = relu(LN_0(x))
    conv_k<<<nodeBlocks, 256, 0, stream>>>(hin, offs, deg, csr, t + 3, tmp, n);
    mlp_fused_k<1, 0><<<mlpGrid, 256, 0, stream>>>(
        tmp, W1 + (size_t)3 * 8192, b1 + 3 * 128, mg + 3 * 128, mb + 3 * 128,
        W2 + (size_t)3 * 8192, b2 + 3 * 64, lng, lnb, xcur, (float*)d_out, n);
}

// Round 15
// 320.586 us; speedup vs baseline: 1.8049x; 1.0369x over previous
//
#include <hip/hip_runtime.h>
#include <hip/hip_bf16.h>

// DeeperGCN (GENConv softmax-agg) on MI355X.
// R13: bf16 activation plane. conv gathers bf16 (halves L2/L3 traffic);
// conv output stored bf16 (= GEMM1's existing rounding point, no new error);
// mlp_fused reads bf16 z directly as MFMA fragments; intermediate relu(LN)
// stored bf16-only. Residual chain xcur stays f32. R12: MFMA MLP = -246us.

typedef unsigned int uint;
typedef unsigned short ushort;
typedef __attribute__((ext_vector_type(8))) short bf16x8;
typedef __attribute__((ext_vector_type(4))) float f32x4;

static __device__ __forceinline__ uint f2bf(float f) {
    uint u = __builtin_bit_cast(uint, f);
    return (u + 0x7FFFu + ((u >> 16) & 1u)) >> 16;   // RNE
}
static __device__ __forceinline__ float bf2f(uint u) {
    return __builtin_bit_cast(float, u << 16);
}
static __device__ __forceinline__ uint4 pk4(float4 a, float4 b) {
    uint4 p;
    p.x = f2bf(a.x) | (f2bf(a.y) << 16);
    p.y = f2bf(a.z) | (f2bf(a.w) << 16);
    p.z = f2bf(b.x) | (f2bf(b.y) << 16);
    p.w = f2bf(b.z) | (f2bf(b.w) << 16);
    return p;
}

union FragU { uint4 u; bf16x8 v; };

#define EPB 4096
#define BCAP 4096

__global__ void zero_bcnt_k(int* __restrict__ p) { p[threadIdx.x] = 0; }

// f32 -> bf16 cast (x plane), vectorized.
__global__ void cast_k(const float* __restrict__ in, ushort* __restrict__ out, int n4) {
    int g = blockIdx.x * blockDim.x + threadIdx.x;
    if (g < n4) {
        float4 v = ((const float4*)in)[g];
        ushort4 o;
        o.x = f2bf(v.x); o.y = f2bf(v.y); o.z = f2bf(v.z); o.w = f2bf(v.w);
        ((ushort4*)out)[g] = o;
    }
}

// CSR pass 1: per-4096-edge block, rank per 128-node bucket via LDS atomics,
// reserve global ranges, append (src,dst) line-locally into staging.
__global__ __launch_bounds__(256) void bucket_scatter_k(const int* __restrict__ src,
                                                        const int* __restrict__ dst,
                                                        int* __restrict__ bcnt,
                                                        int2* __restrict__ stage, int e) {
    __shared__ int lcnt[512];
    __shared__ int lbase[512];
    __shared__ int rkbuf[EPB];
    int tid = threadIdx.x;
    for (int i = tid; i < 512; i += 256) lcnt[i] = 0;
    __syncthreads();
    int i0 = blockIdx.x * EPB;
    int cnt = min(EPB, e - i0);
    for (int k = tid; k < cnt; k += 256) {
        int d = dst[i0 + k];
        rkbuf[k] = atomicAdd(&lcnt[d >> 7], 1);
    }
    __syncthreads();
    for (int i = tid; i < 512; i += 256)
        lbase[i] = lcnt[i] ? atomicAdd(&bcnt[i], lcnt[i]) : 0;
    __syncthreads();
    for (int k = tid; k < cnt; k += 256) {
        int s = src[i0 + k];
        int d = dst[i0 + k];
        int b = d >> 7;
        stage[(size_t)b * BCAP + lbase[b] + rkbuf[k]] = make_int2(s, d);
    }
}

// CSR pass 2: block b drains bucket b; LDS histogram+scan -> bucket-contiguous
// CSR plus offs[]/deg[].
__global__ __launch_bounds__(256) void bucket_to_csr_k(const int2* __restrict__ stage,
                                                       const int* __restrict__ bcnt,
                                                       int* __restrict__ csr,
                                                       int* __restrict__ offs,
                                                       int* __restrict__ deg, int n) {
    __shared__ int lcnt[128];
    __shared__ int loff[128];
    __shared__ int wl[128];
    int b = blockIdx.x;
    int tid = threadIdx.x;
    int base = b << 7;
    if (tid < 128) lcnt[tid] = 0;
    __syncthreads();
    int cnt = bcnt[b];
    const int2* sb = stage + (size_t)b * BCAP;
    for (int k = tid; k < cnt; k += 256)
        atomicAdd(&lcnt[sb[k].y & 127], 1);
    __syncthreads();
    if (tid < 128) loff[tid] = lcnt[tid];
    __syncthreads();
    #pragma unroll
    for (int o = 1; o < 128; o <<= 1) {
        int v = 0;
        if (tid < 128 && tid >= o) v = loff[tid - o];
        __syncthreads();
        if (tid < 128) loff[tid] += v;
        __syncthreads();
    }
    if (tid < 128) {
        int ex = loff[tid] - lcnt[tid];
        wl[tid] = ex;
        if (base + tid < n) {
            offs[base + tid] = b * BCAP + ex;
            deg[base + tid] = lcnt[tid];
        }
    }
    __syncthreads();
    for (int k = tid; k < cnt; k += 256) {
        int2 sd = sb[k];
        int slot = atomicAdd(&wl[sd.y & 127], 1);
        csr[(size_t)b * BCAP + slot] = sd.x;
    }
}

// GENConv softmax aggregation: wave per node, lane = channel. bf16 in/out.
// Online softmax, 8-edge pipelined unroll. out = agg + h (root add), bf16.
__global__ __launch_bounds__(256) void conv_k(const ushort* __restrict__ h,
                                              const int* __restrict__ offs,
                                              const int* __restrict__ deg,
                                              const int* __restrict__ csr,
                                              const float* __restrict__ tptr,
                                              ushort* __restrict__ out, int n) {
    int wid = threadIdx.x >> 6, lane = threadIdx.x & 63;
    int node = blockIdx.x * 4 + wid;
    if (node >= n) return;
    float tt = tptr[0];
    int start = offs[node], d = deg[node];
    float m = -__builtin_huge_valf(), num = 0.f, den = 0.f;
    int i = 0;
    for (; i + 8 <= d; i += 8) {
        int sx[8];
        float v[8];
        #pragma unroll
        for (int q = 0; q < 8; q++) sx[q] = csr[start + i + q];
        #pragma unroll
        for (int q = 0; q < 8; q++) v[q] = bf2f(h[(size_t)sx[q] * 64 + lane]);
        float msg[8], w[8];
        float wm = m;
        #pragma unroll
        for (int q = 0; q < 8; q++) {
            msg[q] = fmaxf(v[q], 0.f) + 1e-7f;
            w[q] = msg[q] * tt;
            wm = fmaxf(wm, w[q]);
        }
        float sc = __expf(m - wm);
        num *= sc; den *= sc;
        #pragma unroll
        for (int q = 0; q < 8; q++) {
            float p = __expf(w[q] - wm);
            num += msg[q] * p;
            den += p;
        }
        m = wm;
    }
    for (; i + 4 <= d; i += 4) {
        int s0 = csr[start + i],     s1 = csr[start + i + 1];
        int s2 = csr[start + i + 2], s3 = csr[start + i + 3];
        float v0 = bf2f(h[(size_t)s0 * 64 + lane]);
        float v1 = bf2f(h[(size_t)s1 * 64 + lane]);
        float v2 = bf2f(h[(size_t)s2 * 64 + lane]);
        float v3 = bf2f(h[(size_t)s3 * 64 + lane]);
        float msg0 = fmaxf(v0, 0.f) + 1e-7f;
        float msg1 = fmaxf(v1, 0.f) + 1e-7f;
        float msg2 = fmaxf(v2, 0.f) + 1e-7f;
        float msg3 = fmaxf(v3, 0.f) + 1e-7f;
        float w0 = msg0 * tt, w1 = msg1 * tt, w2 = msg2 * tt, w3 = msg3 * tt;
        float nm = fmaxf(fmaxf(m, fmaxf(w0, w1)), fmaxf(w2, w3));
        float sc = __expf(m - nm);
        float p0 = __expf(w0 - nm), p1 = __expf(w1 - nm);
        float p2 = __expf(w2 - nm), p3 = __expf(w3 - nm);
        num = num * sc + (msg0 * p0 + msg1 * p1) + (msg2 * p2 + msg3 * p3);
        den = den * sc + (p0 + p1) + (p2 + p3);
        m = nm;
    }
    for (; i < d; i++) {
        int s0 = csr[start + i];
        float v0 = bf2f(h[(size_t)s0 * 64 + lane]);
        float msg0 = fmaxf(v0, 0.f) + 1e-7f;
        float w0 = msg0 * tt;
        float nm = fmaxf(m, w0);
        float sc = __expf(m - nm);
        float p0 = __expf(w0 - nm);
        num = num * sc + msg0 * p0;
        den = den * sc + p0;
        m = nm;
    }
    float agg = num / (den + 1e-16f);
    float hn = bf2f(h[(size_t)node * 64 + lane]);
    out[(size_t)node * 64 + lane] = (ushort)f2bf(agg + hn);
}

// Fused MFMA MLP per 16-node tile (one wave), transposed orientation:
//   C1T = W1.Z^T (bf16 z read directly as B-frags); r = relu(LN(C1T+b1));
//   C2T = W2.R^T (XOR-swizzled LDS bounce); out = C2T+b2 (+xio residual).
// FINAL=0: write xio f32 + hout bf16.  FINAL=1: write hout f32 (d_out) only.
template <int RES, int FINAL>
__global__ __launch_bounds__(256) void mlp_fused_k(
        const ushort* __restrict__ zin,
        const float* __restrict__ W1, const float* __restrict__ b1,
        const float* __restrict__ mg, const float* __restrict__ mb,
        const float* __restrict__ W2, const float* __restrict__ b2,
        const float* __restrict__ g2, const float* __restrict__ bb2,
        float* __restrict__ xio, ushort* __restrict__ houtb,
        float* __restrict__ houtf, int n) {
    __shared__ uint lw1[16 * 64 * 4];
    __shared__ uint lw2[16 * 64 * 4];
    __shared__ uint lrt[4 * 1024];
    __shared__ float sp[576];
    int tid = threadIdx.x;
    int wid = tid >> 6, lane = tid & 63;
    int nodeL = lane & 15, g = lane >> 4;

    #pragma unroll
    for (int q = 0; q < 4; q++) {                    // W1 frags: f = jt*2+ks
        int f = wid * 4 + q;
        int jt = f >> 1, ks = f & 1;
        const float* s = W1 + (jt * 16 + nodeL) * 64 + ks * 32 + g * 8;
        float4 a = *(const float4*)s, b = *(const float4*)(s + 4);
        *(uint4*)&lw1[(f * 64 + lane) * 4] = pk4(a, b);
    }
    #pragma unroll
    for (int q = 0; q < 4; q++) {                    // W2 frags: f = ct*4+ks
        int f = wid * 4 + q;
        int ct = f >> 2, ks = f & 3;
        const float* s = W2 + (ct * 16 + nodeL) * 128 + ks * 32 + g * 8;
        float4 a = *(const float4*)s, b = *(const float4*)(s + 4);
        *(uint4*)&lw2[(f * 64 + lane) * 4] = pk4(a, b);
    }
    if (tid < 128) { sp[tid] = b1[tid]; sp[128 + tid] = mg[tid]; sp[256 + tid] = mb[tid]; }
    else if (tid < 192) {
        int i = tid - 128;
        sp[384 + i] = b2[i]; sp[448 + i] = g2[i]; sp[512 + i] = bb2[i];
    }
    __syncthreads();

    uint* rt = lrt + wid * 1024;
    int nt = (n + 15) >> 4;
    for (int tile = blockIdx.x * 4 + wid; tile < nt; tile += gridDim.x * 4) {
        int node = tile * 16 + nodeL;
        int rnode = min(node, n - 1);
        const ushort* zp = zin + (size_t)rnode * 64;
        FragU zb0, zb1;   // bf16 row IS the fragment layout: k = ks*32+g*8+0..7
        zb0.u = *(const uint4*)(zp + g * 8);
        zb1.u = *(const uint4*)(zp + 32 + g * 8);

        f32x4 acc[8];
        #pragma unroll
        for (int jt = 0; jt < 8; jt++) {
            FragU wA, wB;
            wA.u = *(const uint4*)&lw1[((jt * 2 + 0) * 64 + lane) * 4];
            wB.u = *(const uint4*)&lw1[((jt * 2 + 1) * 64 + lane) * 4];
            f32x4 c = {0.f, 0.f, 0.f, 0.f};
            c = __builtin_amdgcn_mfma_f32_16x16x32_bf16(wA.v, zb0.v, c, 0, 0, 0);
            c = __builtin_amdgcn_mfma_f32_16x16x32_bf16(wB.v, zb1.v, c, 0, 0, 0);
            acc[jt] = c;
        }
        float s1 = 0.f, s2 = 0.f;
        float h[8][4];
        #pragma unroll
        for (int jt = 0; jt < 8; jt++)
            #pragma unroll
            for (int jj = 0; jj < 4; jj++) {
                float v = acc[jt][jj] + sp[jt * 16 + 4 * g + jj];
                h[jt][jj] = v; s1 += v; s2 += v * v;
            }
        s1 += __shfl_xor(s1, 16); s1 += __shfl_xor(s1, 32);
        s2 += __shfl_xor(s2, 16); s2 += __shfl_xor(s2, 32);
        float mu = s1 * (1.f / 128.f);
        float var = s2 * (1.f / 128.f) - mu * mu;
        float rstd = rsqrtf(fmaxf(var, 0.f) + 1e-5f);
        #pragma unroll
        for (int jt = 0; jt < 8; jt++)
            #pragma unroll
            for (int jp = 0; jp < 2; jp++) {
                int j0 = jt * 16 + 4 * g + 2 * jp;
                float r0 = fmaxf((h[jt][2 * jp] - mu) * rstd * sp[128 + j0] + sp[256 + j0], 0.f);
                float r1 = fmaxf((h[jt][2 * jp + 1] - mu) * rstd * sp[128 + j0 + 1] + sp[256 + j0 + 1], 0.f);
                uint val = f2bf(r0) | (f2bf(r1) << 16);
                uint byte = (uint)(nodeL * 256 + jt * 32 + g * 8 + jp * 4) ^ ((uint)nodeL << 4);
                rt[byte >> 2] = val;
            }
        FragU rb[4];
        #pragma unroll
        for (int ks = 0; ks < 4; ks++) {
            uint byte = (uint)(nodeL * 256 + ks * 64 + g * 16) ^ ((uint)nodeL << 4);
            rb[ks].u = *(const uint4*)((const char*)rt + byte);
        }
        f32x4 acc2[4];
        #pragma unroll
        for (int ct = 0; ct < 4; ct++) {
            f32x4 c = {0.f, 0.f, 0.f, 0.f};
            #pragma unroll
            for (int ks = 0; ks < 4; ks++) {
                FragU wf;
                wf.u = *(const uint4*)&lw2[((ct * 4 + ks) * 64 + lane) * 4];
                c = __builtin_amdgcn_mfma_f32_16x16x32_bf16(wf.v, rb[ks].v, c, 0, 0, 0);
            }
            acc2[ct] = c;
        }
        if (node < n) {
            float o[4][4];
            float t1 = 0.f, t2 = 0.f;
            #pragma unroll
            for (int ct = 0; ct < 4; ct++) {
                float4 res;
                if (RES) res = *(const float4*)(xio + (size_t)node * 64 + ct * 16 + 4 * g);
                #pragma unroll
                for (int jj = 0; jj < 4; jj++) {
                    float v = acc2[ct][jj] + sp[384 + ct * 16 + 4 * g + jj];
                    if (RES) v += ((const float*)&res)[jj];
                    o[ct][jj] = v; t1 += v; t2 += v * v;
                }
                if (!FINAL) *(float4*)(xio + (size_t)node * 64 + ct * 16 + 4 * g) =
                    make_float4(o[ct][0], o[ct][1], o[ct][2], o[ct][3]);
            }
            t1 += __shfl_xor(t1, 16); t1 += __shfl_xor(t1, 32);
            t2 += __shfl_xor(t2, 16); t2 += __shfl_xor(t2, 32);
            float mu2 = t1 * (1.f / 64.f);
            float var2 = t2 * (1.f / 64.f) - mu2 * mu2;
            float rs2 = rsqrtf(fmaxf(var2, 0.f) + 1e-5f);
            #pragma unroll
            for (int ct = 0; ct < 4; ct++) {
                float ln0 = fmaxf((o[ct][0] - mu2) * rs2 * sp[448 + ct * 16 + 4 * g + 0] + sp[512 + ct * 16 + 4 * g + 0], 0.f);
                float ln1 = fmaxf((o[ct][1] - mu2) * rs2 * sp[448 + ct * 16 + 4 * g + 1] + sp[512 + ct * 16 + 4 * g + 1], 0.f);
                float ln2 = fmaxf((o[ct][2] - mu2) * rs2 * sp[448 + ct * 16 + 4 * g + 2] + sp[512 + ct * 16 + 4 * g + 2], 0.f);
                float ln3 = fmaxf((o[ct][3] - mu2) * rs2 * sp[448 + ct * 16 + 4 * g + 3] + sp[512 + ct * 16 + 4 * g + 3], 0.f);
                if (FINAL) {
                    *(float4*)(houtf + (size_t)node * 64 + ct * 16 + 4 * g) =
                        make_float4(ln0, ln1, ln2, ln3);
                } else {
                    ushort4 ov;
                    ov.x = f2bf(ln0); ov.y = f2bf(ln1); ov.z = f2bf(ln2); ov.w = f2bf(ln3);
                    *(ushort4*)(houtb + (size_t)node * 64 + ct * 16 + 4 * g) = ov;
                }
            }
        }
    }
}

extern "C" void kernel_launch(void* const* d_in, const int* in_sizes, int n_in,
                              void* d_out, int out_size, void* d_ws, size_t ws_size,
                              hipStream_t stream) {
    const float* x   = (const float*)d_in[0];
    const int*   ei  = (const int*)d_in[1];
    const float* t   = (const float*)d_in[2];
    const float* W1  = (const float*)d_in[3];
    const float* b1  = (const float*)d_in[4];
    const float* mg  = (const float*)d_in[5];
    const float* mb  = (const float*)d_in[6];
    const float* W2  = (const float*)d_in[7];
    const float* b2  = (const float*)d_in[8];
    const float* lng = (const float*)d_in[9];
    const float* lnb = (const float*)d_in[10];

    int n = in_sizes[0] / 64;
    int e = in_sizes[1] / 2;
    const int* src = ei;
    const int* dst = ei + e;

    char* ws = (char*)d_ws;
    size_t off = 0;
    auto alloc = [&](size_t bytes) -> void* {
        void* p = ws + off;
        off = (off + bytes + 255) & ~(size_t)255;
        return p;
    };
    int*    bcnt  = (int*)alloc(512 * 4);
    int*    offs  = (int*)alloc((size_t)n * 4);
    int*    deg   = (int*)alloc((size_t)n * 4);
    int*    csr   = (int*)alloc((size_t)512 * BCAP * 4);
    float*  xcur  = (float*)alloc((size_t)n * 64 * 4);
    ushort* xb    = (ushort*)alloc((size_t)n * 64 * 2);
    ushort* hb    = (ushort*)alloc((size_t)n * 64 * 2);
    ushort* tmpb  = (ushort*)alloc((size_t)n * 64 * 2);
    int2*   stage = (int2*)alloc((size_t)512 * BCAP * 8);

    int nbuck = (n + 127) >> 7;
    zero_bcnt_k<<<1, 512, 0, stream>>>(bcnt);
    bucket_scatter_k<<<(e + EPB - 1) / EPB, 256, 0, stream>>>(src, dst, bcnt, stage, e);
    bucket_to_csr_k<<<nbuck, 256, 0, stream>>>(stage, bcnt, csr, offs, deg, n);
    cast_k<<<(n * 16 + 255) / 256, 256, 0, stream>>>(x, xb, n * 16);

    int nodeBlocks = (n + 3) / 4;
    const int mlpGrid = 512;

    // layer 0: x = mlp(conv(xb)); hb = relu(LN_1(x))
    conv_k<<<nodeBlocks, 256, 0, stream>>>(xb, offs, deg, csr, t + 0, tmpb, n);
    mlp_fused_k<0, 0><<<mlpGrid, 256, 0, stream>>>(tmpb, W1, b1, mg, mb, W2, b2,
                                                   lng + 64, lnb + 64, xcur, hb, nullptr, n);
    // layers 1..2
    for (int i = 1; i <= 2; i++) {
        conv_k<<<nodeBlocks, 256, 0, stream>>>(hb, offs, deg, csr, t + i, tmpb, n);
        mlp_fused_k<1, 0><<<mlpGrid, 256, 0, stream>>>(
            tmpb, W1 + (size_t)i * 8192, b1 + i * 128, mg + i * 128, mb + i * 128,
            W2 + (size_t)i * 8192, b2 + i * 64,
            lng + (i + 1) * 64, lnb + (i + 1) * 64, xcur, hb, nullptr, n);
    }
    // layer 3: d_out = relu(LN_0(x + mlp(conv(hb))))
    conv_k<<<nodeBlocks, 256, 0, stream>>>(hb, offs, deg, csr, t + 3, tmpb, n);
    mlp_fused_k<1, 1><<<mlpGrid, 256, 0, stream>>>(
        tmpb, W1 + (size_t)3 * 8192, b1 + 3 * 128, mg + 3 * 128, mb + 3 * 128,
        W2 + (size_t)3 * 8192, b2 + 3 * 64, lng, lnb, xcur, nullptr, (float*)d_out, n);
}